// Round 5
// baseline (56.482 us; speedup 1.0000x reference)
//
#include <hip/hip_runtime.h>

#define NPOS 8192
#define NNEG 40960
#define NEDGE (NPOS + NNEG)
#define DIM 128
#define MARGIN 0.1f

// ws layout: acc[0]=A, acc[1]=Sp, acc[2]=Sn, ((unsigned*)acc)[3]=done counter,
// sims at wsf+64.

// -------- kernel 1: sims. 1536 blocks x 4 waves, 8 consecutive edges/wave ----
// (8 | NPOS so each wave's 8 edges are all-pos or all-neg -> uniform branch.)
// Block 0 thread 0 zeroes accumulators + done counter (stream-ordered before
// pair_kernel; hipMemsetAsync cost 41us/replay in R3, same-address atomics
// cost 160us in R2 -- this does neither).
__global__ __launch_bounds__(256) void sims_kernel(
    const float* __restrict__ emb,
    const int* __restrict__ pos_idx,
    const int* __restrict__ neg_idx,
    float* __restrict__ sims, float* __restrict__ acc) {
  if (blockIdx.x == 0 && threadIdx.x == 0) {
    acc[0] = 0.f; acc[1] = 0.f; acc[2] = 0.f;
    ((unsigned*)acc)[3] = 0u;
  }
  const int tid = threadIdx.x;
  const int lane = tid & 63;
  const int wave = blockIdx.x * 4 + (tid >> 6);
  const int e0 = wave * 8;
  const int* idx;
  int off, stride;
  if (e0 < NPOS) { idx = pos_idx; off = e0;        stride = NPOS; }
  else           { idx = neg_idx; off = e0 - NPOS; stride = NNEG; }
#pragma unroll
  for (int k = 0; k < 8; ++k) {
    const int s = idx[off + k];
    const int d = idx[stride + off + k];
    const float2 a = *(const float2*)(emb + (long long)s * DIM + lane * 2);
    const float2 b = *(const float2*)(emb + (long long)d * DIM + lane * 2);
    float v = a.x * b.x + a.y * b.y;
#pragma unroll
    for (int m = 32; m >= 1; m >>= 1) v += __shfl_xor(v, m, 64);
    if (lane == 0) sims[e0 + k] = v;
  }
}

// -------- kernel 2: A = sum |n_j - (p_i - M)| + Sp/Sn sides + fused finalize -
// grid = 16 pos-chunks (512 each) x 80 neg-segments (512 each) = 1280 blocks
//      = exactly 5 blocks/CU (balanced).
#define POSC 512
#define NEGSEG 512
#define PAIR_BLOCKS ((NPOS / POSC) * (NNEG / NEGSEG))  // 1280

__global__ __launch_bounds__(256) void pair_kernel(
    const float* __restrict__ sims, float* __restrict__ acc,
    float* __restrict__ out) {
  __shared__ float sneg[NEGSEG];
  const float* pos = sims;
  const float* neg = sims + NPOS;
  const int pc = blockIdx.x & 15;  // pos chunk
  const int ns = blockIdx.x >> 4;  // neg segment
  const int tid = threadIdx.x;

  for (int t = tid; t < NEGSEG; t += 256) sneg[t] = neg[ns * NEGSEG + t];

  const int pb = pc * POSC + tid;
  const float q0 = pos[pb]       - MARGIN;
  const float q1 = pos[pb + 256] - MARGIN;
  __syncthreads();

  float a0 = 0.f, a1 = 0.f, a2 = 0.f, a3 = 0.f;
#pragma unroll 4
  for (int j = 0; j < NEGSEG; j += 4) {
    const float4 n = *(const float4*)(sneg + j);
    a0 += fabsf(n.x - q0); a1 += fabsf(n.x - q1);
    a2 += fabsf(n.y - q0); a3 += fabsf(n.y - q1);
    a0 += fabsf(n.z - q0); a1 += fabsf(n.z - q1);
    a2 += fabsf(n.w - q0); a3 += fabsf(n.w - q1);
  }

  float a = (a0 + a1) + (a2 + a3);
  // Side reductions:
  //   ns==0 blocks (16): sum q over their pos chunk -> Sp = sum_q + POSC*M
  //   pc==0 blocks (80): sum their neg segment      -> Sn
  float e1 = (ns == 0) ? (q0 + q1) : 0.f;
  float e2 = (pc == 0) ? (sneg[tid] + sneg[tid + 256]) : 0.f;
#pragma unroll
  for (int m = 32; m >= 1; m >>= 1) {
    a  += __shfl_xor(a, m, 64);
    e1 += __shfl_xor(e1, m, 64);
    e2 += __shfl_xor(e2, m, 64);
  }
  __shared__ float wa[4], w1[4], w2[4];
  if ((tid & 63) == 0) {
    wa[tid >> 6] = a; w1[tid >> 6] = e1; w2[tid >> 6] = e2;
  }
  __syncthreads();
  if (tid == 0) {
    atomicAdd(acc, (wa[0] + wa[1]) + (wa[2] + wa[3]));
    if (ns == 0)
      atomicAdd(acc + 1,
                (w1[0] + w1[1]) + (w1[2] + w1[3]) + (float)POSC * MARGIN);
    if (pc == 0)
      atomicAdd(acc + 2, (w2[0] + w2[1]) + (w2[2] + w2[3]));
    __threadfence();  // order acc adds before done-counter increment
    const unsigned old = atomicAdd((unsigned*)acc + 3, 1u);
    if (old == PAIR_BLOCKS - 1) {
      // Last block: all 1280 acc-adds are fenced-before their counter
      // increments -> agent-scope acquire loads see the final values.
      const float A  = __hip_atomic_load(acc + 0, __ATOMIC_ACQUIRE,
                                         __HIP_MEMORY_SCOPE_AGENT);
      const float Sp = __hip_atomic_load(acc + 1, __ATOMIC_ACQUIRE,
                                         __HIP_MEMORY_SCOPE_AGENT);
      const float Sn = __hip_atomic_load(acc + 2, __ATOMIC_ACQUIRE,
                                         __HIP_MEMORY_SCOPE_AGENT);
      // S = sum_{i,j} (MARGIN - p_i + n_j); loss = 0.5*(S+A)/(NPOS*NNEG)
      const double S = (double)NNEG * ((double)NPOS * (double)MARGIN -
                                       (double)Sp) +
                       (double)NPOS * (double)Sn;
      out[0] = (float)(0.5 * (S + (double)A) /
                       ((double)NPOS * (double)NNEG));  // LAMBDA_STRUCT = 1.0
    }
  }
}

extern "C" void kernel_launch(void* const* d_in, const int* in_sizes, int n_in,
                              void* d_out, int out_size, void* d_ws, size_t ws_size,
                              hipStream_t stream) {
  const float* emb = (const float*)d_in[0];
  const int* pos_idx = (const int*)d_in[1];
  const int* neg_idx = (const int*)d_in[2];
  float* out = (float*)d_out;

  float* wsf = (float*)d_ws;
  float* acc = wsf;        // 3 float accumulators + 1 uint done counter
  float* sims = wsf + 64;  // 49152 floats of sims (pos then neg)

  // kernel 1: 6144 waves x 8 edges (also zeroes acc + counter)
  sims_kernel<<<NEDGE / 32, 256, 0, stream>>>(emb, pos_idx, neg_idx, sims, acc);

  // kernel 2: balanced 1280 blocks; last finished block writes out[0]
  pair_kernel<<<PAIR_BLOCKS, 256, 0, stream>>>(sims, acc, out);
}

// Round 6
// 38.723 us; speedup vs baseline: 1.4586x; 1.4586x over previous
//
#include <hip/hip_runtime.h>

#define NPOS 8192
#define NNEG 40960
#define NEDGE (NPOS + NNEG)
#define DIM 128
#define MARGIN 0.1f

// No atomics, no fences anywhere (R2: 12K same-addr atomics = 160us;
// R5: 2656 same-line atomics + 1280 threadfences = 42us). Per-block partial
// slots + tiny reduce kernel instead.

// -------- kernel 1: sims. 4 waves/block, 8 consecutive edges per wave -------
__global__ __launch_bounds__(256) void sims_kernel(
    const float* __restrict__ emb,
    const int* __restrict__ pos_idx,
    const int* __restrict__ neg_idx,
    float* __restrict__ sims) {
  const int tid = threadIdx.x;
  const int lane = tid & 63;
  const int wave = blockIdx.x * 4 + (tid >> 6);
  const int e0 = wave * 8;
  const int* idx;
  int off, stride;
  if (e0 < NPOS) { idx = pos_idx; off = e0;        stride = NPOS; }
  else           { idx = neg_idx; off = e0 - NPOS; stride = NNEG; }
#pragma unroll
  for (int k = 0; k < 8; ++k) {
    const int s = idx[off + k];
    const int d = idx[stride + off + k];
    const float2 a = *(const float2*)(emb + (long long)s * DIM + lane * 2);
    const float2 b = *(const float2*)(emb + (long long)d * DIM + lane * 2);
    float v = a.x * b.x + a.y * b.y;
#pragma unroll
    for (int m = 32; m >= 1; m >>= 1) v += __shfl_xor(v, m, 64);
    if (lane == 0) sims[e0 + k] = v;
  }
}

// -------- kernel 2: per-block partials of A = sum |n_j - (p_i - M)| ---------
// grid = 8 pos-chunks (1024) x 160 neg-segments (256) = 1280 blocks = 5/CU.
#define POSC 1024
#define NEGSEG 256
#define NPC (NPOS / POSC)        // 8
#define NNS (NNEG / NEGSEG)      // 160
#define PAIR_BLOCKS (NPC * NNS)  // 1280

__global__ __launch_bounds__(256) void pair_kernel(
    const float* __restrict__ sims, float* __restrict__ pA,
    float* __restrict__ pSp, float* __restrict__ pSn) {
  __shared__ float sneg[NEGSEG];
  const float* pos = sims;
  const float* neg = sims + NPOS;
  const int pc = blockIdx.x & (NPC - 1);  // pos chunk
  const int ns = blockIdx.x >> 3;         // neg segment
  const int tid = threadIdx.x;

  sneg[tid] = neg[ns * NEGSEG + tid];

  const int pb = pc * POSC + tid;
  const float q0 = pos[pb]       - MARGIN;
  const float q1 = pos[pb + 256] - MARGIN;
  const float q2 = pos[pb + 512] - MARGIN;
  const float q3 = pos[pb + 768] - MARGIN;
  __syncthreads();

  float a0 = 0.f, a1 = 0.f, a2 = 0.f, a3 = 0.f;
#pragma unroll 4
  for (int j = 0; j < NEGSEG; j += 4) {
    const float4 n = *(const float4*)(sneg + j);
    a0 += fabsf(n.x - q0); a1 += fabsf(n.x - q1);
    a2 += fabsf(n.x - q2); a3 += fabsf(n.x - q3);
    a0 += fabsf(n.y - q0); a1 += fabsf(n.y - q1);
    a2 += fabsf(n.y - q2); a3 += fabsf(n.y - q3);
    a0 += fabsf(n.z - q0); a1 += fabsf(n.z - q1);
    a2 += fabsf(n.z - q2); a3 += fabsf(n.z - q3);
    a0 += fabsf(n.w - q0); a1 += fabsf(n.w - q1);
    a2 += fabsf(n.w - q2); a3 += fabsf(n.w - q3);
  }

  float a = (a0 + a1) + (a2 + a3);
  // Side sums: ns==0 blocks (8) -> pSp[pc] = sum(p) over chunk;
  //            pc==0 blocks (160) -> pSn[ns] = sum(n) over segment.
  float e1 = (ns == 0) ? ((q0 + q1) + (q2 + q3)) : 0.f;
  float e2 = (pc == 0) ? sneg[tid] : 0.f;
#pragma unroll
  for (int m = 32; m >= 1; m >>= 1) {
    a  += __shfl_xor(a, m, 64);
    e1 += __shfl_xor(e1, m, 64);
    e2 += __shfl_xor(e2, m, 64);
  }
  __shared__ float wa[4], w1[4], w2[4];
  if ((tid & 63) == 0) {
    wa[tid >> 6] = a; w1[tid >> 6] = e1; w2[tid >> 6] = e2;
  }
  __syncthreads();
  if (tid == 0) {
    pA[blockIdx.x] = (wa[0] + wa[1]) + (wa[2] + wa[3]);
    if (ns == 0)
      pSp[pc] = (w1[0] + w1[1]) + (w1[2] + w1[3]) + (float)POSC * MARGIN;
    if (pc == 0)
      pSn[ns] = (w2[0] + w2[1]) + (w2[2] + w2[3]);
  }
}

// -------- kernel 3: reduce 1448 partials + closed-form combine ---------------
__global__ __launch_bounds__(256) void finalize_kernel(
    const float* __restrict__ pA, const float* __restrict__ pSp,
    const float* __restrict__ pSn, float* __restrict__ out) {
  const int tid = threadIdx.x;
  float sA = 0.f;
  for (int i = tid; i < PAIR_BLOCKS; i += 256) sA += pA[i];
  float sp = (tid < NPC) ? pSp[tid] : 0.f;
  float sn = (tid < NNS) ? pSn[tid] : 0.f;
#pragma unroll
  for (int m = 32; m >= 1; m >>= 1) {
    sA += __shfl_xor(sA, m, 64);
    sp += __shfl_xor(sp, m, 64);
    sn += __shfl_xor(sn, m, 64);
  }
  __shared__ float wA[4], wp[4], wn[4];
  if ((tid & 63) == 0) {
    wA[tid >> 6] = sA; wp[tid >> 6] = sp; wn[tid >> 6] = sn;
  }
  __syncthreads();
  if (tid == 0) {
    const double A  = (double)((wA[0] + wA[1]) + (wA[2] + wA[3]));
    const double Sp = (double)((wp[0] + wp[1]) + (wp[2] + wp[3]));
    const double Sn = (double)((wn[0] + wn[1]) + (wn[2] + wn[3]));
    // S = sum_{i,j} (MARGIN - p_i + n_j); loss = 0.5*(S+A)/(NPOS*NNEG)
    const double S = (double)NNEG * ((double)NPOS * (double)MARGIN - Sp) +
                     (double)NPOS * Sn;
    out[0] = (float)(0.5 * (S + A) / ((double)NPOS * (double)NNEG));
  }
}

extern "C" void kernel_launch(void* const* d_in, const int* in_sizes, int n_in,
                              void* d_out, int out_size, void* d_ws, size_t ws_size,
                              hipStream_t stream) {
  const float* emb = (const float*)d_in[0];
  const int* pos_idx = (const int*)d_in[1];
  const int* neg_idx = (const int*)d_in[2];
  float* out = (float*)d_out;

  float* wsf = (float*)d_ws;
  float* sims = wsf;                 // 49152 floats (pos then neg)
  float* pA   = wsf + NEDGE;         // 1280 per-block partials
  float* pSp  = pA + PAIR_BLOCKS;    // 8 pos-chunk sums
  float* pSn  = pSp + NPC;           // 160 neg-segment sums
  // Every slot is overwritten every call -> no zero-init, no atomics.

  sims_kernel<<<NEDGE / 32, 256, 0, stream>>>(emb, pos_idx, neg_idx, sims);
  pair_kernel<<<PAIR_BLOCKS, 256, 0, stream>>>(sims, pA, pSp, pSn);
  finalize_kernel<<<1, 256, 0, stream>>>(pA, pSp, pSn, out);
}